// Round 1
// baseline (760.974 us; speedup 1.0000x reference)
//
#include <hip/hip_runtime.h>
#include <hip/hip_bf16.h>

typedef __bf16 bf16;
typedef __bf16 bf16x4 __attribute__((ext_vector_type(4)));
typedef __bf16 bf16x8 __attribute__((ext_vector_type(8)));
typedef float  f32x4  __attribute__((ext_vector_type(4)));

#define NT 8192   // tokens = B*S
#define DD 1024   // model dim
#define HH 1408   // expert hidden
#define NE 8      // experts
#define NSLOT (NT*2)

#define GLD16(gp, lp) __builtin_amdgcn_global_load_lds( \
    (const __attribute__((address_space(1))) void*)(gp), \
    (__attribute__((address_space(3))) void*)(lp), 16, 0, 0)

// ---------------- x -> bf16 ----------------
__global__ __launch_bounds__(256) void cvt_x_kernel(const float* __restrict__ x,
                                                    bf16* __restrict__ xb) {
  int i = blockIdx.x * 256 + threadIdx.x;
  float4 v = ((const float4*)x)[i];
  bf16x4 o;
  o[0] = (bf16)v.x; o[1] = (bf16)v.y; o[2] = (bf16)v.z; o[3] = (bf16)v.w;
  ((bf16x4*)xb)[i] = o;
}

// ------- transpose+convert: src f32 [R][C] -> dst bf16 [C][R], mat = blockIdx.z -------
__global__ __launch_bounds__(256) void tpose_kernel(const float* __restrict__ src,
                                                    bf16* __restrict__ dst, int R, int C) {
  __shared__ float tile[32][33];
  size_t base = (size_t)blockIdx.z * R * C;
  src += base; dst += base;
  int c0 = blockIdx.x * 32, r0 = blockIdx.y * 32;
  int tx = threadIdx.x & 31, ty = threadIdx.x >> 5;  // 32x8
  for (int i = 0; i < 4; i++)
    tile[ty + 8 * i][tx] = src[(size_t)(r0 + ty + 8 * i) * C + (c0 + tx)];
  __syncthreads();
  for (int i = 0; i < 4; i++)
    dst[(size_t)(c0 + ty + 8 * i) * R + (r0 + tx)] = (bf16)tile[tx][ty + 8 * i];
}

// ---------------- router: 1 wave/token, fp64 accum, softmax+top2, atomic append ----------------
__global__ __launch_bounds__(256) void router_kernel(const float* __restrict__ x,
                                                     const float* __restrict__ wrt,
                                                     int* __restrict__ counts,
                                                     int* __restrict__ tok,
                                                     float* __restrict__ gates) {
  __shared__ float swr[NE * DD];  // 32 KB
  int tid = threadIdx.x;
  {
    const float4* g4 = (const float4*)wrt;
    float4* s4 = (float4*)swr;
    for (int i = 0; i < 8; i++) s4[tid + 256 * i] = g4[tid + 256 * i];
  }
  __syncthreads();
  int wave = tid >> 6, lane = tid & 63;
  int t = blockIdx.x * 4 + wave;
  double acc[NE];
  for (int e = 0; e < NE; e++) acc[e] = 0.0;
  const float4* xt = (const float4*)(x + (size_t)t * DD);
  const float4* s4 = (const float4*)swr;
  for (int i = 0; i < 4; i++) {
    float4 xv = xt[lane + 64 * i];
    for (int e = 0; e < NE; e++) {
      float4 wv = s4[e * 256 + lane + 64 * i];
      acc[e] += (double)xv.x * wv.x + (double)xv.y * wv.y +
                (double)xv.z * wv.z + (double)xv.w * wv.w;
    }
  }
  for (int e = 0; e < NE; e++)
    for (int off = 32; off > 0; off >>= 1)
      acc[e] += __shfl_xor(acc[e], off, 64);
  if (lane == 0) {
    double m = acc[0];
    for (int e = 1; e < NE; e++) if (acc[e] > m) m = acc[e];
    double p[NE], s = 0.0;
    for (int e = 0; e < NE; e++) { p[e] = exp(acc[e] - m); s += p[e]; }
    int i1 = 0;
    for (int e = 1; e < NE; e++) if (p[e] > p[i1]) i1 = e;   // ties -> lower index
    int i2 = (i1 == 0) ? 1 : 0;
    for (int e = 0; e < NE; e++) if (e != i1 && p[e] > p[i2]) i2 = e;
    float g1 = (float)(p[i1] / s), g2 = (float)(p[i2] / s);
    int pos = atomicAdd(&counts[i1], 1); tok[i1 * NT + pos] = t; gates[i1 * NT + pos] = g1;
    pos = atomicAdd(&counts[i2], 1);     tok[i2 * NT + pos] = t; gates[i2 * NT + pos] = g2;
  }
}

__global__ void prefix_kernel(const int* __restrict__ counts, int* __restrict__ offs) {
  if (threadIdx.x == 0) {
    int s = 0;
    for (int e = 0; e < NE; e++) { offs[e] = s; s += counts[e]; }
  }
}

// ---------------- GEMM1: h = silu(Xg @ w1) * (Xg @ w3), gathered rows, per expert ----------------
// A: gathered xb rows [cnt][DD]; B^T: w1t/w3t [HH][DD]; out h bf16 [slot][HH]
__global__ __launch_bounds__(256, 2) void gemm1_kernel(
    const bf16* __restrict__ xb, const bf16* __restrict__ w1t, const bf16* __restrict__ w3t,
    const int* __restrict__ tok, const int* __restrict__ counts, const int* __restrict__ offs,
    bf16* __restrict__ hbuf) {
  const int e = blockIdx.z;
  const int cnt = counts[e];
  const int m0 = blockIdx.x * 128;
  if (m0 >= cnt) return;
  const int n0 = blockIdx.y * 128;
  const int hbase = offs[e];
  __shared__ alignas(16) bf16 sA[128 * 64];
  __shared__ alignas(16) bf16 sB1[128 * 64];
  __shared__ alignas(16) bf16 sB3[128 * 64];
  const int tid = threadIdx.x, wave = tid >> 6, lane = tid & 63;
  const int srow = lane >> 3;         // row within 8-row chunk
  const int skk = (lane & 7) * 8;     // bf16 k-offset within row (16B granule)
  const bf16* w1e = w1t + (size_t)e * HH * DD;
  const bf16* w3e = w3t + (size_t)e * HH * DD;
  const bf16* aptr[4]; const bf16* b1ptr[4]; const bf16* b3ptr[4];
  for (int i = 0; i < 4; i++) {
    int c = wave * 4 + i;
    int r = c * 8 + srow;
    int gr = m0 + r; if (gr >= cnt) gr = cnt - 1;          // clamp pad rows
    aptr[i]  = xb  + (size_t)tok[e * NT + gr] * DD + skk;
    b1ptr[i] = w1e + (size_t)(n0 + r) * DD + skk;
    b3ptr[i] = w3e + (size_t)(n0 + r) * DD + skk;
  }
  f32x4 acc1[4][4], acc3[4][4];
  f32x4 zero = {0.f, 0.f, 0.f, 0.f};
  for (int mi = 0; mi < 4; mi++)
    for (int ni = 0; ni < 4; ni++) { acc1[mi][ni] = zero; acc3[mi][ni] = zero; }
  const int wr_ = wave >> 1, wc_ = wave & 1;
  const int mbase = wr_ * 64, nbase = wc_ * 64;
  for (int kt = 0; kt < DD / 64; ++kt) {
    const int kb = kt * 64;
    for (int i = 0; i < 4; i++) {
      int c = wave * 4 + i;
      GLD16(aptr[i]  + kb, sA  + c * 512);
      GLD16(b1ptr[i] + kb, sB1 + c * 512);
      GLD16(b3ptr[i] + kb, sB3 + c * 512);
    }
    __syncthreads();
#pragma unroll
    for (int ks = 0; ks < 2; ++ks) {
      bf16x8 af[4], bf1[4], bf3[4];
#pragma unroll
      for (int mi = 0; mi < 4; mi++)
        af[mi] = *(const bf16x8*)(sA + (mbase + mi * 16 + (lane & 15)) * 64 + ks * 32 + (lane >> 4) * 8);
#pragma unroll
      for (int ni = 0; ni < 4; ni++) {
        int rr = (nbase + ni * 16 + (lane & 15)) * 64 + ks * 32 + (lane >> 4) * 8;
        bf1[ni] = *(const bf16x8*)(sB1 + rr);
        bf3[ni] = *(const bf16x8*)(sB3 + rr);
      }
#pragma unroll
      for (int mi = 0; mi < 4; mi++)
#pragma unroll
        for (int ni = 0; ni < 4; ni++) {
          acc1[mi][ni] = __builtin_amdgcn_mfma_f32_16x16x32_bf16(af[mi], bf1[ni], acc1[mi][ni], 0, 0, 0);
          acc3[mi][ni] = __builtin_amdgcn_mfma_f32_16x16x32_bf16(af[mi], bf3[ni], acc3[mi][ni], 0, 0, 0);
        }
    }
    __syncthreads();
  }
  // epilogue: h = silu(a1)*a3 -> bf16
  const int col = lane & 15;
  const int rb = (lane >> 4) * 4;
#pragma unroll
  for (int mi = 0; mi < 4; mi++)
#pragma unroll
    for (int r = 0; r < 4; r++) {
      int grow = m0 + mbase + mi * 16 + rb + r;
      if (grow < cnt) {
        bf16* hrow = hbuf + (size_t)(hbase + grow) * HH + n0 + nbase + col;
#pragma unroll
        for (int ni = 0; ni < 4; ni++) {
          float v1 = acc1[mi][ni][r], v3 = acc3[mi][ni][r];
          float hv = v1 / (1.f + __expf(-v1)) * v3;
          hrow[ni * 16] = (bf16)hv;
        }
      }
    }
}

// ---------------- GEMM2: y = h @ w2, scatter out[tok] += gate*y ----------------
__global__ __launch_bounds__(256, 2) void gemm2_kernel(
    const bf16* __restrict__ hbuf, const bf16* __restrict__ w2t,
    const int* __restrict__ tok, const float* __restrict__ gates,
    const int* __restrict__ counts, const int* __restrict__ offs,
    float* __restrict__ out) {
  const int e = blockIdx.z;
  const int cnt = counts[e];
  const int m0 = blockIdx.x * 128;
  if (m0 >= cnt) return;
  const int n0 = blockIdx.y * 128;
  const int hbase = offs[e];
  __shared__ alignas(16) bf16 sA[128 * 64];
  __shared__ alignas(16) bf16 sB[128 * 64];
  const int tid = threadIdx.x, wave = tid >> 6, lane = tid & 63;
  const int srow = lane >> 3;
  const int skk = (lane & 7) * 8;
  const bf16* w2e = w2t + (size_t)e * DD * HH;
  const bf16* aptr[4]; const bf16* bptr[4];
  for (int i = 0; i < 4; i++) {
    int c = wave * 4 + i;
    int r = c * 8 + srow;
    int gr = m0 + r; if (gr >= cnt) gr = cnt - 1;
    aptr[i] = hbuf + (size_t)(hbase + gr) * HH + skk;
    bptr[i] = w2e + (size_t)(n0 + r) * HH + skk;
  }
  f32x4 acc[4][4];
  f32x4 zero = {0.f, 0.f, 0.f, 0.f};
  for (int mi = 0; mi < 4; mi++)
    for (int ni = 0; ni < 4; ni++) acc[mi][ni] = zero;
  const int wr_ = wave >> 1, wc_ = wave & 1;
  const int mbase = wr_ * 64, nbase = wc_ * 64;
  for (int kt = 0; kt < HH / 64; ++kt) {
    const int kb = kt * 64;
    for (int i = 0; i < 4; i++) {
      int c = wave * 4 + i;
      GLD16(aptr[i] + kb, sA + c * 512);
      GLD16(bptr[i] + kb, sB + c * 512);
    }
    __syncthreads();
#pragma unroll
    for (int ks = 0; ks < 2; ++ks) {
      bf16x8 af[4], bfr[4];
#pragma unroll
      for (int mi = 0; mi < 4; mi++)
        af[mi] = *(const bf16x8*)(sA + (mbase + mi * 16 + (lane & 15)) * 64 + ks * 32 + (lane >> 4) * 8);
#pragma unroll
      for (int ni = 0; ni < 4; ni++)
        bfr[ni] = *(const bf16x8*)(sB + (nbase + ni * 16 + (lane & 15)) * 64 + ks * 32 + (lane >> 4) * 8);
#pragma unroll
      for (int mi = 0; mi < 4; mi++)
#pragma unroll
        for (int ni = 0; ni < 4; ni++)
          acc[mi][ni] = __builtin_amdgcn_mfma_f32_16x16x32_bf16(af[mi], bfr[ni], acc[mi][ni], 0, 0, 0);
    }
    __syncthreads();
  }
  const int col = lane & 15;
  const int rb = (lane >> 4) * 4;
#pragma unroll
  for (int mi = 0; mi < 4; mi++)
#pragma unroll
    for (int r = 0; r < 4; r++) {
      int grow = m0 + mbase + mi * 16 + rb + r;
      if (grow < cnt) {
        int t = tok[e * NT + grow];
        float g = gates[e * NT + grow];
        float* orow = out + (size_t)t * DD + n0 + nbase + col;
#pragma unroll
        for (int ni = 0; ni < 4; ni++)
          atomicAdd(orow + ni * 16, g * acc[mi][ni][r]);
      }
    }
}

extern "C" void kernel_launch(void* const* d_in, const int* in_sizes, int n_in,
                              void* d_out, int out_size, void* d_ws, size_t ws_size,
                              hipStream_t stream) {
  const float* x  = (const float*)d_in[0];
  const float* wr = (const float*)d_in[1];
  const float* w1 = (const float*)d_in[2];
  const float* w2 = (const float*)d_in[3];   // note: dict order x, w_router, w1, w2, w3
  const float* w3 = (const float*)d_in[4];
  float* out = (float*)d_out;

  char* ws = (char*)d_ws;
  size_t off = 0;
  auto alloc = [&](size_t bytes) { void* p = ws + off; off += (bytes + 255) & ~(size_t)255; return p; };
  bf16* xb    = (bf16*)alloc((size_t)NT * DD * 2);        // 16.8 MB
  bf16* w1t   = (bf16*)alloc((size_t)NE * HH * DD * 2);   // 23.1 MB  [E][H][D]
  bf16* w3t   = (bf16*)alloc((size_t)NE * HH * DD * 2);   // 23.1 MB
  bf16* w2t   = (bf16*)alloc((size_t)NE * DD * HH * 2);   // 23.1 MB  [E][D][H]
  bf16* hbuf  = (bf16*)alloc((size_t)NSLOT * HH * 2);     // 46.1 MB
  int*  tok   = (int*)alloc((size_t)NE * NT * 4);
  float* gates= (float*)alloc((size_t)NE * NT * 4);
  int*  counts= (int*)alloc(256);
  int*  offs  = (int*)alloc(256);
  (void)ws_size; (void)in_sizes; (void)n_in;

  hipMemsetAsync(d_out, 0, (size_t)out_size * 4, stream);
  hipMemsetAsync(counts, 0, 256, stream);

  cvt_x_kernel<<<NT * DD / 4 / 256, 256, 0, stream>>>(x, xb);
  tpose_kernel<<<dim3(HH / 32, DD / 32, NE), 256, 0, stream>>>(w1, w1t, DD, HH);
  tpose_kernel<<<dim3(HH / 32, DD / 32, NE), 256, 0, stream>>>(w3, w3t, DD, HH);
  tpose_kernel<<<dim3(DD / 32, HH / 32, NE), 256, 0, stream>>>(w2, w2t, HH, DD);
  router_kernel<<<NT / 4, 256, 0, stream>>>(x, wr, counts, tok, gates);
  prefix_kernel<<<1, 64, 0, stream>>>(counts, offs);
  gemm1_kernel<<<dim3(NT / 128, HH / 128, NE), 256, 0, stream>>>(xb, w1t, w3t, tok, counts, offs, hbuf);
  gemm2_kernel<<<dim3(NT / 128, DD / 128, NE), 256, 0, stream>>>(hbuf, w2t, tok, gates, counts, offs, out);
}

// Round 4
// 640.904 us; speedup vs baseline: 1.1873x; 1.1873x over previous
//
#include <hip/hip_runtime.h>
#include <hip/hip_bf16.h>

typedef __bf16 bf16;
typedef __bf16 bf16x4 __attribute__((ext_vector_type(4)));
typedef __bf16 bf16x8 __attribute__((ext_vector_type(8)));
typedef float  f32x4  __attribute__((ext_vector_type(4)));

#define NT 8192   // tokens = B*S
#define DD 1024   // model dim
#define HH 1408   // expert hidden
#define NE 8      // experts
#define NSLOT (NT*2)

#define GLD16(gp, lp) __builtin_amdgcn_global_load_lds( \
    (const __attribute__((address_space(1))) void*)(gp), \
    (__attribute__((address_space(3))) void*)(lp), 16, 0, 0)

#define MFMA_BF16 __builtin_amdgcn_mfma_f32_16x16x32_bf16

// ---------------- x -> bf16 ----------------
__global__ __launch_bounds__(256) void cvt_x_kernel(const float* __restrict__ x,
                                                    bf16* __restrict__ xb) {
  int i = blockIdx.x * 256 + threadIdx.x;
  float4 v = ((const float4*)x)[i];
  bf16x4 o;
  o[0] = (bf16)v.x; o[1] = (bf16)v.y; o[2] = (bf16)v.z; o[3] = (bf16)v.w;
  ((bf16x4*)xb)[i] = o;
}

// ------- transpose+convert: src f32 [R][C] -> dst bf16 [C][R], mat = blockIdx.z -------
__global__ __launch_bounds__(256) void tpose_kernel(const float* __restrict__ src,
                                                    bf16* __restrict__ dst, int R, int C) {
  __shared__ float tile[32][33];
  size_t base = (size_t)blockIdx.z * R * C;
  src += base; dst += base;
  int c0 = blockIdx.x * 32, r0 = blockIdx.y * 32;
  int tx = threadIdx.x & 31, ty = threadIdx.x >> 5;  // 32x8
  for (int i = 0; i < 4; i++)
    tile[ty + 8 * i][tx] = src[(size_t)(r0 + ty + 8 * i) * C + (c0 + tx)];
  __syncthreads();
  for (int i = 0; i < 4; i++)
    dst[(size_t)(c0 + ty + 8 * i) * R + (r0 + tx)] = (bf16)tile[tx][ty + 8 * i];
}

// ---------------- router: 1 wave/token, fp64 accum, softmax+top2 ----------------
__global__ __launch_bounds__(256) void router_kernel(const float* __restrict__ x,
                                                     const float* __restrict__ wrt,
                                                     int* __restrict__ counts,
                                                     int* __restrict__ tok,
                                                     unsigned int* __restrict__ info,
                                                     float* __restrict__ gtab) {
  __shared__ float swr[NE * DD];  // 32 KB
  int tid = threadIdx.x;
  {
    const float4* g4 = (const float4*)wrt;
    float4* s4 = (float4*)swr;
    for (int i = 0; i < 8; i++) s4[tid + 256 * i] = g4[tid + 256 * i];
  }
  __syncthreads();
  int wave = tid >> 6, lane = tid & 63;
  int t = blockIdx.x * 4 + wave;
  double acc[NE];
  for (int e = 0; e < NE; e++) acc[e] = 0.0;
  const float4* xt = (const float4*)(x + (size_t)t * DD);
  const float4* s4 = (const float4*)swr;
  for (int i = 0; i < 4; i++) {
    float4 xv = xt[lane + 64 * i];
    for (int e = 0; e < NE; e++) {
      float4 wv = s4[e * 256 + lane + 64 * i];
      acc[e] += (double)xv.x * wv.x + (double)xv.y * wv.y +
                (double)xv.z * wv.z + (double)xv.w * wv.w;
    }
  }
  for (int e = 0; e < NE; e++)
    for (int off = 32; off > 0; off >>= 1)
      acc[e] += __shfl_xor(acc[e], off, 64);
  if (lane == 0) {
    double m = acc[0];
    for (int e = 1; e < NE; e++) if (acc[e] > m) m = acc[e];
    double p[NE], s = 0.0;
    for (int e = 0; e < NE; e++) { p[e] = exp(acc[e] - m); s += p[e]; }
    int i1 = 0;
    for (int e = 1; e < NE; e++) if (p[e] > p[i1]) i1 = e;   // ties -> lower index
    int i2 = (i1 == 0) ? 1 : 0;
    for (int e = 0; e < NE; e++) if (e != i1 && p[e] > p[i2]) i2 = e;
    float g1 = (float)(p[i1] / s), g2 = (float)(p[i2] / s);
    int pos = atomicAdd(&counts[i1], 1);
    tok[i1 * NT + pos] = t; info[t * 2] = ((unsigned)i1 << 16) | pos; gtab[t * 2] = g1;
    pos = atomicAdd(&counts[i2], 1);
    tok[i2 * NT + pos] = t; info[t * 2 + 1] = ((unsigned)i2 << 16) | pos; gtab[t * 2 + 1] = g2;
  }
}

__global__ void prefix_kernel(const int* __restrict__ counts, int* __restrict__ offs) {
  if (threadIdx.x == 0) {
    int s = 0;
    for (int e = 0; e < NE; e++) { offs[e] = s; s += counts[e]; }
  }
}

// ---------------- GEMM1: h = silu(Xg @ w1) * (Xg @ w3) ----------------
// 512 thr, 8 waves (2M x 4N), 128x128 tile, BK=64, dbuf LDS 96KB, counted vmcnt,
// XOR-granule swizzle (pre-swizzled global source + swizzled ds_read).
__global__ __launch_bounds__(512, 2) void gemm1_kernel(
    const bf16* __restrict__ xb, const bf16* __restrict__ w1t, const bf16* __restrict__ w3t,
    const int* __restrict__ tok, const int* __restrict__ counts, const int* __restrict__ offs,
    bf16* __restrict__ hbuf) {
  __shared__ alignas(16) bf16 sA[2][128 * 64];
  __shared__ alignas(16) bf16 sB1[2][128 * 64];
  __shared__ alignas(16) bf16 sB3[2][128 * 64];
  // nwg = 64*11*8 = 5632 = 8*704 ; XCD-chunked: expert = bid&7 pinned to one XCD
  const int bid = blockIdx.x;
  const int swz = (bid & 7) * 704 + (bid >> 3);
  const int e   = swz / 704;
  const int rem = swz % 704;          // 704 = 64*11, m fastest
  const int n0  = (rem / 64) * 128;
  const int m0  = (rem % 64) * 128;
  const int cnt = counts[e];
  if (m0 >= cnt) return;
  const int hbase = offs[e];
  const int tid = threadIdx.x, wave = tid >> 6, lane = tid & 63;
  // staging geometry: chunk = round*8 + wave covers rows chunk*8 .. +8 (128B rows)
  const int lrow = lane >> 3;                      // 0..7 row within chunk
  const int sg   = ((lane & 7) ^ lrow) * 8;        // swizzled source granule (elems)
  const int r0 = wave * 8 + lrow;                  // rows 0..63
  const int r1 = r0 + 64;                          // rows 64..127
  int gr0 = m0 + r0; if (gr0 >= cnt) gr0 = cnt - 1;
  int gr1 = m0 + r1; if (gr1 >= cnt) gr1 = cnt - 1;
  const bf16* w1e = w1t + (size_t)e * HH * DD;
  const bf16* w3e = w3t + (size_t)e * HH * DD;
  const bf16* a0  = xb  + (size_t)tok[e * NT + gr0] * DD + sg;
  const bf16* a1  = xb  + (size_t)tok[e * NT + gr1] * DD + sg;
  const bf16* b10 = w1e + (size_t)(n0 + r0) * DD + sg;
  const bf16* b11 = w1e + (size_t)(n0 + r1) * DD + sg;
  const bf16* b30 = w3e + (size_t)(n0 + r0) * DD + sg;
  const bf16* b31 = w3e + (size_t)(n0 + r1) * DD + sg;
  const int lc0 = wave * 512;          // LDS chunk bases (elements)
  const int lc1 = (8 + wave) * 512;

  f32x4 acc1[4][2], acc3[4][2];
  const f32x4 zero = {0.f, 0.f, 0.f, 0.f};
  for (int mi = 0; mi < 4; mi++)
    for (int ni = 0; ni < 2; ni++) { acc1[mi][ni] = zero; acc3[mi][ni] = zero; }
  const int wr_ = wave >> 2, wc_ = wave & 3;
  const int mbase = wr_ * 64, nbase = wc_ * 32;
  const int fr = lane & 15, fq = lane >> 4;

  // prologue: stage tile 0
  GLD16(a0, sA[0] + lc0);  GLD16(a1, sA[0] + lc1);
  GLD16(b10, sB1[0] + lc0); GLD16(b11, sB1[0] + lc1);
  GLD16(b30, sB3[0] + lc0); GLD16(b31, sB3[0] + lc1);

  for (int kt = 0; kt < DD / 64; ++kt) {
    const int cur = kt & 1;
    if (kt < DD / 64 - 1) {
      const int nx = cur ^ 1, kb = (kt + 1) * 64;
      GLD16(a0 + kb, sA[nx] + lc0);  GLD16(a1 + kb, sA[nx] + lc1);
      GLD16(b10 + kb, sB1[nx] + lc0); GLD16(b11 + kb, sB1[nx] + lc1);
      GLD16(b30 + kb, sB3[nx] + lc0); GLD16(b31 + kb, sB3[nx] + lc1);
      asm volatile("s_waitcnt vmcnt(6)" ::: "memory");   // wait current tile, keep 6 in flight
    } else {
      asm volatile("s_waitcnt vmcnt(0)" ::: "memory");
    }
    __builtin_amdgcn_s_barrier();
    __builtin_amdgcn_sched_barrier(0);
    const bf16* tA = sA[cur]; const bf16* tB1 = sB1[cur]; const bf16* tB3 = sB3[cur];
#pragma unroll
    for (int ks = 0; ks < 2; ++ks) {
      bf16x8 af[4], f1[2], f3[2];
      const int gl = ks * 4 + fq;
#pragma unroll
      for (int mi = 0; mi < 4; mi++) {
        int r = mbase + mi * 16 + fr;
        af[mi] = *(const bf16x8*)(tA + r * 64 + ((gl ^ (r & 7)) * 8));
      }
#pragma unroll
      for (int ni = 0; ni < 2; ni++) {
        int r = nbase + ni * 16 + fr;
        int off = r * 64 + ((gl ^ (r & 7)) * 8);
        f1[ni] = *(const bf16x8*)(tB1 + off);
        f3[ni] = *(const bf16x8*)(tB3 + off);
      }
#pragma unroll
      for (int mi = 0; mi < 4; mi++)
#pragma unroll
        for (int ni = 0; ni < 2; ni++) {
          acc1[mi][ni] = MFMA_BF16(af[mi], f1[ni], acc1[mi][ni], 0, 0, 0);
          acc3[mi][ni] = MFMA_BF16(af[mi], f3[ni], acc3[mi][ni], 0, 0, 0);
        }
    }
    __builtin_amdgcn_sched_barrier(0);
    __builtin_amdgcn_s_barrier();
  }
  // epilogue: h = silu(a1)*a3 -> bf16
  const int col = lane & 15;
  const int rb = fq * 4;
#pragma unroll
  for (int mi = 0; mi < 4; mi++)
#pragma unroll
    for (int r = 0; r < 4; r++) {
      int grow = m0 + mbase + mi * 16 + rb + r;
      if (grow < cnt) {
        bf16* hrow = hbuf + (size_t)(hbase + grow) * HH + n0 + nbase + col;
#pragma unroll
        for (int ni = 0; ni < 2; ni++) {
          float v1 = acc1[mi][ni][r], v3 = acc3[mi][ni][r];
          hrow[ni * 16] = (bf16)(v1 / (1.f + __expf(-v1)) * v3);
        }
      }
    }
}

// ---------------- GEMM2: ybuf[slot] = h @ w2 (ungated) ----------------
__global__ __launch_bounds__(512, 2) void gemm2_kernel(
    const bf16* __restrict__ hbuf, const bf16* __restrict__ w2t,
    const int* __restrict__ counts, const int* __restrict__ offs,
    bf16* __restrict__ ybuf) {
  __shared__ alignas(16) bf16 sA[2][128 * 64];
  __shared__ alignas(16) bf16 sB[2][128 * 64];
  // nwg = 64*8*8 = 4096 = 8*512
  const int bid = blockIdx.x;
  const int swz = (bid & 7) * 512 + (bid >> 3);
  const int e   = swz / 512;
  const int rem = swz % 512;          // 512 = 64*8
  const int n0  = (rem / 64) * 128;
  const int m0  = (rem % 64) * 128;
  const int cnt = counts[e];
  if (m0 >= cnt) return;
  const int hbase = offs[e];
  const int tid = threadIdx.x, wave = tid >> 6, lane = tid & 63;
  const int lrow = lane >> 3;
  const int sg   = ((lane & 7) ^ lrow) * 8;
  const int r0 = wave * 8 + lrow;
  const int r1 = r0 + 64;
  int gr0 = m0 + r0; if (gr0 >= cnt) gr0 = cnt - 1;
  int gr1 = m0 + r1; if (gr1 >= cnt) gr1 = cnt - 1;
  const bf16* w2e = w2t + (size_t)e * DD * HH;
  const bf16* a0 = hbuf + (size_t)(hbase + gr0) * HH + sg;
  const bf16* a1 = hbuf + (size_t)(hbase + gr1) * HH + sg;
  const bf16* b0 = w2e + (size_t)(n0 + r0) * HH + sg;
  const bf16* b1 = w2e + (size_t)(n0 + r1) * HH + sg;
  const int lc0 = wave * 512, lc1 = (8 + wave) * 512;

  f32x4 acc[4][2];
  const f32x4 zero = {0.f, 0.f, 0.f, 0.f};
  for (int mi = 0; mi < 4; mi++)
    for (int ni = 0; ni < 2; ni++) acc[mi][ni] = zero;
  const int wr_ = wave >> 2, wc_ = wave & 3;
  const int mbase = wr_ * 64, nbase = wc_ * 32;
  const int fr = lane & 15, fq = lane >> 4;

  GLD16(a0, sA[0] + lc0); GLD16(a1, sA[0] + lc1);
  GLD16(b0, sB[0] + lc0); GLD16(b1, sB[0] + lc1);

  for (int kt = 0; kt < HH / 64; ++kt) {
    const int cur = kt & 1;
    if (kt < HH / 64 - 1) {
      const int nx = cur ^ 1, kb = (kt + 1) * 64;
      GLD16(a0 + kb, sA[nx] + lc0); GLD16(a1 + kb, sA[nx] + lc1);
      GLD16(b0 + kb, sB[nx] + lc0); GLD16(b1 + kb, sB[nx] + lc1);
      asm volatile("s_waitcnt vmcnt(4)" ::: "memory");
    } else {
      asm volatile("s_waitcnt vmcnt(0)" ::: "memory");
    }
    __builtin_amdgcn_s_barrier();
    __builtin_amdgcn_sched_barrier(0);
    const bf16* tA = sA[cur]; const bf16* tB = sB[cur];
#pragma unroll
    for (int ks = 0; ks < 2; ++ks) {
      bf16x8 af[4], bfr[2];
      const int gl = ks * 4 + fq;
#pragma unroll
      for (int mi = 0; mi < 4; mi++) {
        int r = mbase + mi * 16 + fr;
        af[mi] = *(const bf16x8*)(tA + r * 64 + ((gl ^ (r & 7)) * 8));
      }
#pragma unroll
      for (int ni = 0; ni < 2; ni++) {
        int r = nbase + ni * 16 + fr;
        bfr[ni] = *(const bf16x8*)(tB + r * 64 + ((gl ^ (r & 7)) * 8));
      }
#pragma unroll
      for (int mi = 0; mi < 4; mi++)
#pragma unroll
        for (int ni = 0; ni < 2; ni++)
          acc[mi][ni] = MFMA_BF16(af[mi], bfr[ni], acc[mi][ni], 0, 0, 0);
    }
    __builtin_amdgcn_sched_barrier(0);
    __builtin_amdgcn_s_barrier();
  }
  const int col = lane & 15;
  const int rb = fq * 4;
#pragma unroll
  for (int mi = 0; mi < 4; mi++)
#pragma unroll
    for (int r = 0; r < 4; r++) {
      int grow = m0 + mbase + mi * 16 + rb + r;
      if (grow < cnt) {
        bf16* yrow = ybuf + (size_t)(hbase + grow) * DD + n0 + nbase + col;
#pragma unroll
        for (int ni = 0; ni < 2; ni++)
          yrow[ni * 16] = (bf16)acc[mi][ni][r];
      }
    }
}

// ---------------- combine: out[t] = g0*y[slot0] + g1*y[slot1] ----------------
__global__ __launch_bounds__(256) void combine_kernel(
    const bf16* __restrict__ ybuf, const unsigned int* __restrict__ info,
    const float* __restrict__ gtab, const int* __restrict__ offs,
    float* __restrict__ out) {
  const int t = blockIdx.x;
  const unsigned i0 = info[t * 2], i1 = info[t * 2 + 1];
  const float g0 = gtab[t * 2], g1 = gtab[t * 2 + 1];
  const int s0 = offs[i0 >> 16] + (int)(i0 & 0xFFFF);
  const int s1 = offs[i1 >> 16] + (int)(i1 & 0xFFFF);
  const bf16x4* y0 = (const bf16x4*)(ybuf + (size_t)s0 * DD);
  const bf16x4* y1 = (const bf16x4*)(ybuf + (size_t)s1 * DD);
  float4* o = (float4*)(out + (size_t)t * DD);
  const int i = threadIdx.x;
  bf16x4 a = y0[i], b = y1[i];
  float4 r;
  r.x = g0 * (float)a[0] + g1 * (float)b[0];
  r.y = g0 * (float)a[1] + g1 * (float)b[1];
  r.z = g0 * (float)a[2] + g1 * (float)b[2];
  r.w = g0 * (float)a[3] + g1 * (float)b[3];
  o[i] = r;
}

extern "C" void kernel_launch(void* const* d_in, const int* in_sizes, int n_in,
                              void* d_out, int out_size, void* d_ws, size_t ws_size,
                              hipStream_t stream) {
  const float* x  = (const float*)d_in[0];
  const float* wr = (const float*)d_in[1];
  const float* w1 = (const float*)d_in[2];
  const float* w2 = (const float*)d_in[3];   // dict order: x, w_router, w1, w2, w3
  const float* w3 = (const float*)d_in[4];
  float* out = (float*)d_out;

  char* ws = (char*)d_ws;
  size_t off = 0;
  auto alloc = [&](size_t bytes) { void* p = ws + off; off += (bytes + 255) & ~(size_t)255; return p; };
  bf16* xb    = (bf16*)alloc((size_t)NT * DD * 2);          // 16.8 MB
  bf16* w1t   = (bf16*)alloc((size_t)NE * HH * DD * 2);     // 23.1 MB  [E][H][D]
  bf16* w3t   = (bf16*)alloc((size_t)NE * HH * DD * 2);     // 23.1 MB
  bf16* w2t   = (bf16*)alloc((size_t)NE * DD * HH * 2);     // 23.1 MB  [E][D][H]
  bf16* hbuf  = (bf16*)alloc((size_t)NSLOT * HH * 2);       // 46.1 MB
  bf16* ybuf  = (bf16*)alloc((size_t)NSLOT * DD * 2);       // 33.6 MB
  int*  tok   = (int*)alloc((size_t)NE * NT * 4);
  unsigned int* info = (unsigned int*)alloc((size_t)NT * 2 * 4);
  float* gtab = (float*)alloc((size_t)NT * 2 * 4);
  int*  counts= (int*)alloc(256);
  int*  offs  = (int*)alloc(256);
  (void)ws_size; (void)in_sizes; (void)n_in;

  hipMemsetAsync(counts, 0, 256, stream);

  cvt_x_kernel<<<NT * DD / 4 / 256, 256, 0, stream>>>(x, xb);
  tpose_kernel<<<dim3(HH / 32, DD / 32, NE), 256, 0, stream>>>(w1, w1t, DD, HH);
  tpose_kernel<<<dim3(HH / 32, DD / 32, NE), 256, 0, stream>>>(w3, w3t, DD, HH);
  tpose_kernel<<<dim3(DD / 32, HH / 32, NE), 256, 0, stream>>>(w2, w2t, HH, DD);
  router_kernel<<<NT / 4, 256, 0, stream>>>(x, wr, counts, tok, info, gtab);
  prefix_kernel<<<1, 64, 0, stream>>>(counts, offs);
  gemm1_kernel<<<64 * 11 * NE, 512, 0, stream>>>(xb, w1t, w3t, tok, counts, offs, hbuf);
  gemm2_kernel<<<64 * 8 * NE, 512, 0, stream>>>(hbuf, w2t, counts, offs, ybuf);
  combine_kernel<<<NT, 256, 0, stream>>>(ybuf, info, gtab, offs, out);
}

// Round 5
// 461.367 us; speedup vs baseline: 1.6494x; 1.3891x over previous
//
#include <hip/hip_runtime.h>
#include <hip/hip_bf16.h>

typedef __bf16 bf16;
typedef __bf16 bf16x4 __attribute__((ext_vector_type(4)));
typedef __bf16 bf16x8 __attribute__((ext_vector_type(8)));
typedef float  f32x4  __attribute__((ext_vector_type(4)));

#define NT 8192   // tokens = B*S
#define DD 1024   // model dim
#define HH 1408   // expert hidden
#define NE 8      // experts
#define NSLOT (NT*2)

#define GLD16(gp, lp) __builtin_amdgcn_global_load_lds( \
    (const __attribute__((address_space(1))) void*)(gp), \
    (__attribute__((address_space(3))) void*)(lp), 16, 0, 0)

#define MFMA_BF16 __builtin_amdgcn_mfma_f32_16x16x32_bf16

// ---------------- x -> bf16 ----------------
__global__ __launch_bounds__(256) void cvt_x_kernel(const float* __restrict__ x,
                                                    bf16* __restrict__ xb) {
  int i = blockIdx.x * 256 + threadIdx.x;
  float4 v = ((const float4*)x)[i];
  bf16x4 o;
  o[0] = (bf16)v.x; o[1] = (bf16)v.y; o[2] = (bf16)v.z; o[3] = (bf16)v.w;
  ((bf16x4*)xb)[i] = o;
}

// ------- transpose+convert: src f32 [R][C] -> dst bf16 [C][R], mat = blockIdx.z -------
// 64x64 tile; transpose at LDS-write (stride 65 -> 2-way banks, free); f32x4 global
// loads; bf16x4 stores coalesced in 128B chunks per output row.
__global__ __launch_bounds__(256) void tpose_kernel(const float* __restrict__ src,
                                                    bf16* __restrict__ dst, int R, int C) {
  __shared__ float tile[64][65];   // tile[c][r]
  size_t base = (size_t)blockIdx.z * R * C;
  src += base; dst += base;
  const int x0 = blockIdx.x * 64;   // col block (src C)
  const int y0 = blockIdx.y * 64;   // row block (src R)
  const int tid = threadIdx.x;
  const int rr = tid >> 4;          // 0..15
  const int q  = tid & 15;          // 0..15
#pragma unroll
  for (int i = 0; i < 4; i++) {
    int r = i * 16 + rr;
    float4 v = *(const float4*)(src + (size_t)(y0 + r) * C + x0 + q * 4);
    tile[q * 4 + 0][r] = v.x;
    tile[q * 4 + 1][r] = v.y;
    tile[q * 4 + 2][r] = v.z;
    tile[q * 4 + 3][r] = v.w;
  }
  __syncthreads();
#pragma unroll
  for (int i = 0; i < 4; i++) {
    int c = i * 16 + rr;
    bf16x4 v;
#pragma unroll
    for (int j = 0; j < 4; j++) v[j] = (bf16)tile[c][q * 4 + j];
    *(bf16x4*)(dst + (size_t)(x0 + c) * R + y0 + q * 4) = v;
  }
}

// ---------------- score: 1 wave/token, fp64 accum, top2 + gates, NO atomics ----------------
__global__ __launch_bounds__(256) void score_kernel(const float* __restrict__ x,
                                                    const float* __restrict__ wrt,
                                                    unsigned int* __restrict__ einfo,
                                                    float* __restrict__ gtab) {
  __shared__ float swr[NE * DD];  // 32 KB
  int tid = threadIdx.x;
  {
    const float4* g4 = (const float4*)wrt;
    float4* s4 = (float4*)swr;
    for (int i = 0; i < 8; i++) s4[tid + 256 * i] = g4[tid + 256 * i];
  }
  __syncthreads();
  int wave = tid >> 6, lane = tid & 63;
  int t = blockIdx.x * 4 + wave;
  double acc[NE];
  for (int e = 0; e < NE; e++) acc[e] = 0.0;
  const float4* xt = (const float4*)(x + (size_t)t * DD);
  const float4* s4 = (const float4*)swr;
  for (int i = 0; i < 4; i++) {
    float4 xv = xt[lane + 64 * i];
    for (int e = 0; e < NE; e++) {
      float4 wv = s4[e * 256 + lane + 64 * i];
      acc[e] += (double)xv.x * wv.x + (double)xv.y * wv.y +
                (double)xv.z * wv.z + (double)xv.w * wv.w;
    }
  }
  for (int e = 0; e < NE; e++)
    for (int off = 32; off > 0; off >>= 1)
      acc[e] += __shfl_xor(acc[e], off, 64);
  // all lanes hold all 8 scores; selection uniform across lanes (no divergence)
  int i1 = 0;
  for (int e = 1; e < NE; e++) if (acc[e] > acc[i1]) i1 = e;   // ties -> lower index
  int i2 = (i1 == 0) ? 1 : 0;
  for (int e = 0; e < NE; e++) if (e != i1 && acc[e] > acc[i2]) i2 = e;
  double m = acc[i1];
  float s = 0.f;
  for (int e = 0; e < NE; e++) s += __expf((float)(acc[e] - m));
  float g1 = 1.0f / s;                                // exp(0)/s
  float g2 = __expf((float)(acc[i2] - m)) / s;
  if (lane == 0) {
    einfo[t] = ((unsigned)i1 << 8) | (unsigned)i2;
    gtab[t * 2] = g1; gtab[t * 2 + 1] = g2;
  }
}

// ---------------- bucket: LDS histogram, 8 global atomics/block (256 total) ----------------
__global__ __launch_bounds__(256) void bucket_kernel(const unsigned int* __restrict__ einfo,
                                                     int* __restrict__ counts,
                                                     int* __restrict__ tok,
                                                     unsigned int* __restrict__ info) {
  __shared__ int lcnt[NE], lbase[NE];
  const int tid = threadIdx.x;
  if (tid < NE) lcnt[tid] = 0;
  __syncthreads();
  const int t = blockIdx.x * 256 + tid;
  const unsigned ei = einfo[t];
  const int e1 = (int)(ei >> 8), e2 = (int)(ei & 0xFF);
  const int p1 = atomicAdd(&lcnt[e1], 1);
  const int p2 = atomicAdd(&lcnt[e2], 1);
  __syncthreads();
  if (tid < NE) lbase[tid] = atomicAdd(&counts[tid], lcnt[tid]);
  __syncthreads();
  const int pos1 = lbase[e1] + p1, pos2 = lbase[e2] + p2;
  tok[e1 * NT + pos1] = t; info[t * 2]     = ((unsigned)e1 << 16) | (unsigned)pos1;
  tok[e2 * NT + pos2] = t; info[t * 2 + 1] = ((unsigned)e2 << 16) | (unsigned)pos2;
}

__global__ void prefix_kernel(const int* __restrict__ counts, int* __restrict__ offs) {
  if (threadIdx.x == 0) {
    int s = 0;
    for (int e = 0; e < NE; e++) { offs[e] = s; s += counts[e]; }
  }
}

// ---------------- GEMM1: h = silu(Xg @ w1) * (Xg @ w3) ----------------
// 512 thr, 8 waves (2M x 4N), 128x128 tile, BK=64, dbuf LDS 96KB, counted vmcnt,
// XOR-granule swizzle (pre-swizzled global source + swizzled ds_read).
__global__ __launch_bounds__(512, 2) void gemm1_kernel(
    const bf16* __restrict__ xb, const bf16* __restrict__ w1t, const bf16* __restrict__ w3t,
    const int* __restrict__ tok, const int* __restrict__ counts, const int* __restrict__ offs,
    bf16* __restrict__ hbuf) {
  __shared__ alignas(16) bf16 sA[2][128 * 64];
  __shared__ alignas(16) bf16 sB1[2][128 * 64];
  __shared__ alignas(16) bf16 sB3[2][128 * 64];
  // nwg = 64*11*8 = 5632 = 8*704 ; XCD-chunked: expert = bid&7 pinned to one XCD
  const int bid = blockIdx.x;
  const int swz = (bid & 7) * 704 + (bid >> 3);
  const int e   = swz / 704;
  const int rem = swz % 704;          // 704 = 64*11, m fastest
  const int n0  = (rem / 64) * 128;
  const int m0  = (rem % 64) * 128;
  const int cnt = counts[e];
  if (m0 >= cnt) return;
  const int hbase = offs[e];
  const int tid = threadIdx.x, wave = tid >> 6, lane = tid & 63;
  const int lrow = lane >> 3;                      // 0..7 row within chunk
  const int sg   = ((lane & 7) ^ lrow) * 8;        // swizzled source granule (elems)
  const int r0 = wave * 8 + lrow;                  // rows 0..63
  const int r1 = r0 + 64;                          // rows 64..127
  int gr0 = m0 + r0; if (gr0 >= cnt) gr0 = cnt - 1;
  int gr1 = m0 + r1; if (gr1 >= cnt) gr1 = cnt - 1;
  const bf16* w1e = w1t + (size_t)e * HH * DD;
  const bf16* w3e = w3t + (size_t)e * HH * DD;
  const bf16* a0  = xb  + (size_t)tok[e * NT + gr0] * DD + sg;
  const bf16* a1  = xb  + (size_t)tok[e * NT + gr1] * DD + sg;
  const bf16* b10 = w1e + (size_t)(n0 + r0) * DD + sg;
  const bf16* b11 = w1e + (size_t)(n0 + r1) * DD + sg;
  const bf16* b30 = w3e + (size_t)(n0 + r0) * DD + sg;
  const bf16* b31 = w3e + (size_t)(n0 + r1) * DD + sg;
  const int lc0 = wave * 512;          // LDS chunk bases (elements)
  const int lc1 = (8 + wave) * 512;

  f32x4 acc1[4][2], acc3[4][2];
  const f32x4 zero = {0.f, 0.f, 0.f, 0.f};
  for (int mi = 0; mi < 4; mi++)
    for (int ni = 0; ni < 2; ni++) { acc1[mi][ni] = zero; acc3[mi][ni] = zero; }
  const int wr_ = wave >> 2, wc_ = wave & 3;
  const int mbase = wr_ * 64, nbase = wc_ * 32;
  const int fr = lane & 15, fq = lane >> 4;

  // prologue: stage tile 0
  GLD16(a0, sA[0] + lc0);  GLD16(a1, sA[0] + lc1);
  GLD16(b10, sB1[0] + lc0); GLD16(b11, sB1[0] + lc1);
  GLD16(b30, sB3[0] + lc0); GLD16(b31, sB3[0] + lc1);

  for (int kt = 0; kt < DD / 64; ++kt) {
    const int cur = kt & 1;
    if (kt < DD / 64 - 1) {
      const int nx = cur ^ 1, kb = (kt + 1) * 64;
      GLD16(a0 + kb, sA[nx] + lc0);  GLD16(a1 + kb, sA[nx] + lc1);
      GLD16(b10 + kb, sB1[nx] + lc0); GLD16(b11 + kb, sB1[nx] + lc1);
      GLD16(b30 + kb, sB3[nx] + lc0); GLD16(b31 + kb, sB3[nx] + lc1);
      asm volatile("s_waitcnt vmcnt(6)" ::: "memory");   // wait current tile, keep 6 in flight
    } else {
      asm volatile("s_waitcnt vmcnt(0)" ::: "memory");
    }
    __builtin_amdgcn_s_barrier();
    __builtin_amdgcn_sched_barrier(0);
    const bf16* tA = sA[cur]; const bf16* tB1 = sB1[cur]; const bf16* tB3 = sB3[cur];
#pragma unroll
    for (int ks = 0; ks < 2; ++ks) {
      bf16x8 af[4], f1[2], f3[2];
      const int gl = ks * 4 + fq;
#pragma unroll
      for (int mi = 0; mi < 4; mi++) {
        int r = mbase + mi * 16 + fr;
        af[mi] = *(const bf16x8*)(tA + r * 64 + ((gl ^ (r & 7)) * 8));
      }
#pragma unroll
      for (int ni = 0; ni < 2; ni++) {
        int r = nbase + ni * 16 + fr;
        int off = r * 64 + ((gl ^ (r & 7)) * 8);
        f1[ni] = *(const bf16x8*)(tB1 + off);
        f3[ni] = *(const bf16x8*)(tB3 + off);
      }
#pragma unroll
      for (int mi = 0; mi < 4; mi++)
#pragma unroll
        for (int ni = 0; ni < 2; ni++) {
          acc1[mi][ni] = MFMA_BF16(af[mi], f1[ni], acc1[mi][ni], 0, 0, 0);
          acc3[mi][ni] = MFMA_BF16(af[mi], f3[ni], acc3[mi][ni], 0, 0, 0);
        }
    }
    __builtin_amdgcn_sched_barrier(0);
    __builtin_amdgcn_s_barrier();
  }
  // epilogue: h = silu(a1)*a3 -> bf16
  const int col = lane & 15;
  const int rb = fq * 4;
#pragma unroll
  for (int mi = 0; mi < 4; mi++)
#pragma unroll
    for (int r = 0; r < 4; r++) {
      int grow = m0 + mbase + mi * 16 + rb + r;
      if (grow < cnt) {
        bf16* hrow = hbuf + (size_t)(hbase + grow) * HH + n0 + nbase + col;
#pragma unroll
        for (int ni = 0; ni < 2; ni++) {
          float v1 = acc1[mi][ni][r], v3 = acc3[mi][ni][r];
          hrow[ni * 16] = (bf16)(v1 / (1.f + __expf(-v1)) * v3);
        }
      }
    }
}

// ---------------- GEMM2: ybuf[slot] = h @ w2 (ungated) ----------------
__global__ __launch_bounds__(512, 2) void gemm2_kernel(
    const bf16* __restrict__ hbuf, const bf16* __restrict__ w2t,
    const int* __restrict__ counts, const int* __restrict__ offs,
    bf16* __restrict__ ybuf) {
  __shared__ alignas(16) bf16 sA[2][128 * 64];
  __shared__ alignas(16) bf16 sB[2][128 * 64];
  // nwg = 64*8*8 = 4096 = 8*512
  const int bid = blockIdx.x;
  const int swz = (bid & 7) * 512 + (bid >> 3);
  const int e   = swz / 512;
  const int rem = swz % 512;          // 512 = 64*8
  const int n0  = (rem / 64) * 128;
  const int m0  = (rem % 64) * 128;
  const int cnt = counts[e];
  if (m0 >= cnt) return;
  const int hbase = offs[e];
  const int tid = threadIdx.x, wave = tid >> 6, lane = tid & 63;
  const int lrow = lane >> 3;
  const int sg   = ((lane & 7) ^ lrow) * 8;
  const int r0 = wave * 8 + lrow;
  const int r1 = r0 + 64;
  int gr0 = m0 + r0; if (gr0 >= cnt) gr0 = cnt - 1;
  int gr1 = m0 + r1; if (gr1 >= cnt) gr1 = cnt - 1;
  const bf16* w2e = w2t + (size_t)e * DD * HH;
  const bf16* a0 = hbuf + (size_t)(hbase + gr0) * HH + sg;
  const bf16* a1 = hbuf + (size_t)(hbase + gr1) * HH + sg;
  const bf16* b0 = w2e + (size_t)(n0 + r0) * HH + sg;
  const bf16* b1 = w2e + (size_t)(n0 + r1) * HH + sg;
  const int lc0 = wave * 512, lc1 = (8 + wave) * 512;

  f32x4 acc[4][2];
  const f32x4 zero = {0.f, 0.f, 0.f, 0.f};
  for (int mi = 0; mi < 4; mi++)
    for (int ni = 0; ni < 2; ni++) acc[mi][ni] = zero;
  const int wr_ = wave >> 2, wc_ = wave & 3;
  const int mbase = wr_ * 64, nbase = wc_ * 32;
  const int fr = lane & 15, fq = lane >> 4;

  GLD16(a0, sA[0] + lc0); GLD16(a1, sA[0] + lc1);
  GLD16(b0, sB[0] + lc0); GLD16(b1, sB[0] + lc1);

  for (int kt = 0; kt < HH / 64; ++kt) {
    const int cur = kt & 1;
    if (kt < HH / 64 - 1) {
      const int nx = cur ^ 1, kb = (kt + 1) * 64;
      GLD16(a0 + kb, sA[nx] + lc0); GLD16(a1 + kb, sA[nx] + lc1);
      GLD16(b0 + kb, sB[nx] + lc0); GLD16(b1 + kb, sB[nx] + lc1);
      asm volatile("s_waitcnt vmcnt(4)" ::: "memory");
    } else {
      asm volatile("s_waitcnt vmcnt(0)" ::: "memory");
    }
    __builtin_amdgcn_s_barrier();
    __builtin_amdgcn_sched_barrier(0);
    const bf16* tA = sA[cur]; const bf16* tB = sB[cur];
#pragma unroll
    for (int ks = 0; ks < 2; ++ks) {
      bf16x8 af[4], bfr[2];
      const int gl = ks * 4 + fq;
#pragma unroll
      for (int mi = 0; mi < 4; mi++) {
        int r = mbase + mi * 16 + fr;
        af[mi] = *(const bf16x8*)(tA + r * 64 + ((gl ^ (r & 7)) * 8));
      }
#pragma unroll
      for (int ni = 0; ni < 2; ni++) {
        int r = nbase + ni * 16 + fr;
        bfr[ni] = *(const bf16x8*)(tB + r * 64 + ((gl ^ (r & 7)) * 8));
      }
#pragma unroll
      for (int mi = 0; mi < 4; mi++)
#pragma unroll
        for (int ni = 0; ni < 2; ni++)
          acc[mi][ni] = MFMA_BF16(af[mi], bfr[ni], acc[mi][ni], 0, 0, 0);
    }
    __builtin_amdgcn_sched_barrier(0);
    __builtin_amdgcn_s_barrier();
  }
  const int col = lane & 15;
  const int rb = fq * 4;
#pragma unroll
  for (int mi = 0; mi < 4; mi++)
#pragma unroll
    for (int r = 0; r < 4; r++) {
      int grow = m0 + mbase + mi * 16 + rb + r;
      if (grow < cnt) {
        bf16* yrow = ybuf + (size_t)(hbase + grow) * DD + n0 + nbase + col;
#pragma unroll
        for (int ni = 0; ni < 2; ni++)
          yrow[ni * 16] = (bf16)acc[mi][ni][r];
      }
    }
}

// ---------------- combine: out[t] = g0*y[slot0] + g1*y[slot1] ----------------
__global__ __launch_bounds__(256) void combine_kernel(
    const bf16* __restrict__ ybuf, const unsigned int* __restrict__ info,
    const float* __restrict__ gtab, const int* __restrict__ offs,
    float* __restrict__ out) {
  const int t = blockIdx.x;
  const unsigned i0 = info[t * 2], i1 = info[t * 2 + 1];
  const float g0 = gtab[t * 2], g1 = gtab[t * 2 + 1];
  const int s0 = offs[i0 >> 16] + (int)(i0 & 0xFFFF);
  const int s1 = offs[i1 >> 16] + (int)(i1 & 0xFFFF);
  const bf16x4* y0 = (const bf16x4*)(ybuf + (size_t)s0 * DD);
  const bf16x4* y1 = (const bf16x4*)(ybuf + (size_t)s1 * DD);
  float4* o = (float4*)(out + (size_t)t * DD);
  const int i = threadIdx.x;
  bf16x4 a = y0[i], b = y1[i];
  float4 r;
  r.x = g0 * (float)a[0] + g1 * (float)b[0];
  r.y = g0 * (float)a[1] + g1 * (float)b[1];
  r.z = g0 * (float)a[2] + g1 * (float)b[2];
  r.w = g0 * (float)a[3] + g1 * (float)b[3];
  o[i] = r;
}

extern "C" void kernel_launch(void* const* d_in, const int* in_sizes, int n_in,
                              void* d_out, int out_size, void* d_ws, size_t ws_size,
                              hipStream_t stream) {
  const float* x  = (const float*)d_in[0];
  const float* wr = (const float*)d_in[1];
  const float* w1 = (const float*)d_in[2];
  const float* w2 = (const float*)d_in[3];   // dict order: x, w_router, w1, w2, w3
  const float* w3 = (const float*)d_in[4];
  float* out = (float*)d_out;

  char* ws = (char*)d_ws;
  size_t off = 0;
  auto alloc = [&](size_t bytes) { void* p = ws + off; off += (bytes + 255) & ~(size_t)255; return p; };
  bf16* xb    = (bf16*)alloc((size_t)NT * DD * 2);          // 16.8 MB
  bf16* w1t   = (bf16*)alloc((size_t)NE * HH * DD * 2);     // 23.1 MB  [E][H][D]
  bf16* w3t   = (bf16*)alloc((size_t)NE * HH * DD * 2);     // 23.1 MB
  bf16* w2t   = (bf16*)alloc((size_t)NE * DD * HH * 2);     // 23.1 MB  [E][D][H]
  bf16* hbuf  = (bf16*)alloc((size_t)NSLOT * HH * 2);       // 46.1 MB
  bf16* ybuf  = (bf16*)alloc((size_t)NSLOT * DD * 2);       // 33.6 MB
  int*  tok   = (int*)alloc((size_t)NE * NT * 4);
  unsigned int* einfo = (unsigned int*)alloc((size_t)NT * 4);
  unsigned int* info  = (unsigned int*)alloc((size_t)NT * 2 * 4);
  float* gtab = (float*)alloc((size_t)NT * 2 * 4);
  int*  counts= (int*)alloc(256);
  int*  offs  = (int*)alloc(256);
  (void)ws_size; (void)in_sizes; (void)n_in;

  hipMemsetAsync(counts, 0, 256, stream);

  cvt_x_kernel<<<NT * DD / 4 / 256, 256, 0, stream>>>(x, xb);
  tpose_kernel<<<dim3(HH / 64, DD / 64, NE), 256, 0, stream>>>(w1, w1t, DD, HH);
  tpose_kernel<<<dim3(HH / 64, DD / 64, NE), 256, 0, stream>>>(w3, w3t, DD, HH);
  tpose_kernel<<<dim3(DD / 64, HH / 64, NE), 256, 0, stream>>>(w2, w2t, HH, DD);
  score_kernel<<<NT / 4, 256, 0, stream>>>(x, wr, einfo, gtab);
  bucket_kernel<<<NT / 256, 256, 0, stream>>>(einfo, counts, tok, info);
  prefix_kernel<<<1, 64, 0, stream>>>(counts, offs);
  gemm1_kernel<<<64 * 11 * NE, 512, 0, stream>>>(xb, w1t, w3t, tok, counts, offs, hbuf);
  gemm2_kernel<<<64 * 8 * NE, 512, 0, stream>>>(hbuf, w2t, counts, offs, ybuf);
  combine_kernel<<<NT, 256, 0, stream>>>(ybuf, info, gtab, offs, out);
}